// Round 4
// baseline (243.892 us; speedup 1.0000x reference)
//
#include <hip/hip_runtime.h>
#include <math.h>

#define B_  8
#define E_  1024
#define D_  256
#define H_  16
#define FF_ 1024
#define M_  (B_ * E_)   // 8192 rows

typedef __attribute__((ext_vector_type(8))) short short8;
typedef __attribute__((ext_vector_type(4))) float f32x4;
typedef unsigned short bf16u;

#define GLOAD_LDS16(g, l) __builtin_amdgcn_global_load_lds( \
    (const __attribute__((address_space(1))) void*)(g), \
    (__attribute__((address_space(3))) void*)(l), 16, 0, 0)

__device__ __forceinline__ unsigned short f2bf(float f) {
  union { float f; unsigned u; } c; c.f = f;
  unsigned r = c.u + 0x7fffu + ((c.u >> 16) & 1u);   // RNE
  return (unsigned short)(r >> 16);
}
__device__ __forceinline__ float gelu_exact(float x) {
  return 0.5f * x * (1.0f + erff(x * 0.70710678118654752f));
}

// ---------------------------------------------------------------------------
// bf16 MFMA GEMM (unchanged — passing). C[M,N] = A @ Wt^T + bias (+epilogue)
// EPI: 0 = bf16 out (+bias); 2 = bf16 gelu.
// ---------------------------------------------------------------------------
template<int BM, int BN, int EPI>
__global__ __launch_bounds__(256) void mm_k(
    const bf16u* __restrict__ A, const bf16u* __restrict__ Wt,
    const float* __restrict__ bias, const float* __restrict__ R,
    void* __restrict__ Cout, int M, int N, int K)
{
  constexpr int WM = BM / 2, WN = BN / 2;
  constexpr int MT = WM / 16, NT = WN / 16;
  constexpr int PA = BM * 8 / 256, PB = BN * 8 / 256;
  constexpr int LBM = (BM == 128 ? 7 : 6), LBN = (BN == 128 ? 7 : 6);
  __shared__ bf16u As[BM * 64];
  __shared__ bf16u Bs[BN * 64];

  const int t = threadIdx.x;
  const int l15 = t & 15, quad = (t >> 4) & 3;
  const int w = t >> 6, wm = w >> 1, wn = w & 1;
  const int m0 = blockIdx.x * BM, n0 = blockIdx.y * BN;

  f32x4 acc[MT][NT];
  const f32x4 z4 = {0.f, 0.f, 0.f, 0.f};
#pragma unroll
  for (int i = 0; i < MT; ++i)
#pragma unroll
    for (int j = 0; j < NT; ++j) acc[i][j] = z4;

  for (int k0 = 0; k0 < K; k0 += 64) {
    __syncthreads();
#pragma unroll
    for (int p = 0; p < PA; ++p) {
      int g = p * 256 + t;
      int m = g & (BM - 1), c = g >> LBM;
      const bf16u* src = A + (size_t)(m0 + m) * K + k0 + c * 8;
      GLOAD_LDS16(src, As + g * 8);
    }
#pragma unroll
    for (int p = 0; p < PB; ++p) {
      int g = p * 256 + t;
      int n = g & (BN - 1), c = g >> LBN;
      const bf16u* src = Wt + (size_t)(n0 + n) * K + k0 + c * 8;
      GLOAD_LDS16(src, Bs + g * 8);
    }
    __syncthreads();
#pragma unroll
    for (int s = 0; s < 2; ++s) {
      short8 af[MT], bfr[NT];
#pragma unroll
      for (int mt = 0; mt < MT; ++mt)
        af[mt] = *(const short8*)(As + ((s * 4 + quad) * BM + wm * WM + mt * 16 + l15) * 8);
#pragma unroll
      for (int nt = 0; nt < NT; ++nt)
        bfr[nt] = *(const short8*)(Bs + ((s * 4 + quad) * BN + wn * WN + nt * 16 + l15) * 8);
#pragma unroll
      for (int mt = 0; mt < MT; ++mt)
#pragma unroll
        for (int nt = 0; nt < NT; ++nt)
          acc[mt][nt] = __builtin_amdgcn_mfma_f32_16x16x32_bf16(
              af[mt], bfr[nt], acc[mt][nt], 0, 0, 0);
    }
  }

#pragma unroll
  for (int mt = 0; mt < MT; ++mt) {
#pragma unroll
    for (int nt = 0; nt < NT; ++nt) {
      int col = n0 + wn * WN + nt * 16 + l15;
      float bia = bias[col];
#pragma unroll
      for (int r = 0; r < 4; ++r) {
        int row = m0 + wm * WM + mt * 16 + quad * 4 + r;
        size_t idx = (size_t)row * N + col;
        float v = acc[mt][nt][r] + bia;
        if (EPI == 2) { ((bf16u*)Cout)[idx] = f2bf(gelu_exact(v)); }
        else          { ((bf16u*)Cout)[idx] = f2bf(v); }
      }
    }
  }
}

// ---------------------------------------------------------------------------
// Fused GEMM + bias + residual + LayerNorm.  BN = 256 = full row width.
// BM=32, BK=64, 256 thr = 4 waves (1 x 4 in n), wave tile 32x64 (MT=2,NT=4).
// Grid = M/32 = 256 blocks. Epilogue: v = acc + bias + R (fp32); per-row
// stats via shfl_xor over l15 + LDS cross-wave combine (red[2][32][4]);
// y = (v-mu)*rs*gamma + beta.  LN1: write Yf fp32 + Yb bf16. else: Yf only.
// ---------------------------------------------------------------------------
template<int K_, int LN1>
__global__ __launch_bounds__(256) void mm_ln_k(
    const bf16u* __restrict__ A, const bf16u* __restrict__ Wt,
    const float* __restrict__ bias, const float* __restrict__ R,
    const float* __restrict__ gam, const float* __restrict__ bet,
    float* __restrict__ Yf, bf16u* __restrict__ Yb)
{
  __shared__ bf16u As[32 * 64];    // 4 KB,  layout [c][m], c = 16B k-chunk
  __shared__ bf16u Bs[256 * 64];   // 32 KB, layout [c][n]
  __shared__ float red[2][32][4];  // per-row {sum,sumsq} partial per n-wave

  const int t = threadIdx.x;
  const int l15 = t & 15, quad = (t >> 4) & 3;
  const int w = t >> 6;            // n-wave 0..3
  const int m0 = blockIdx.x * 32;

  f32x4 acc[2][4];
  const f32x4 z4 = {0.f, 0.f, 0.f, 0.f};
#pragma unroll
  for (int i = 0; i < 2; ++i)
#pragma unroll
    for (int j = 0; j < 4; ++j) acc[i][j] = z4;

  for (int k0 = 0; k0 < K_; k0 += 64) {
    __syncthreads();
    {  // As: 256 chunks, one per thread (g = t = c*32+m)
      const bf16u* src = A + (size_t)(m0 + (t & 31)) * K_ + k0 + (t >> 5) * 8;
      GLOAD_LDS16(src, As + t * 8);
    }
#pragma unroll
    for (int p = 0; p < 8; ++p) {  // Bs: 2048 chunks (g = c*256+n)
      int g = p * 256 + t;
      const bf16u* src = Wt + (size_t)(g & 255) * K_ + k0 + (g >> 8) * 8;
      GLOAD_LDS16(src, Bs + g * 8);
    }
    __syncthreads();
#pragma unroll
    for (int s = 0; s < 2; ++s) {
      const int cc = s * 4 + quad;
      short8 af[2], bfr[4];
#pragma unroll
      for (int mt = 0; mt < 2; ++mt)
        af[mt] = *(const short8*)(As + (cc * 32 + mt * 16 + l15) * 8);
#pragma unroll
      for (int nt = 0; nt < 4; ++nt)
        bfr[nt] = *(const short8*)(Bs + (cc * 256 + w * 64 + nt * 16 + l15) * 8);
#pragma unroll
      for (int mt = 0; mt < 2; ++mt)
#pragma unroll
        for (int nt = 0; nt < 4; ++nt)
          acc[mt][nt] = __builtin_amdgcn_mfma_f32_16x16x32_bf16(
              af[mt], bfr[nt], acc[mt][nt], 0, 0, 0);
    }
  }

  // ---- epilogue: bias + residual, then per-row LN over all 256 cols ----
  float ga[4], be4[4], bi[4];
#pragma unroll
  for (int nt = 0; nt < 4; ++nt) {
    int col = w * 64 + nt * 16 + l15;
    bi[nt] = bias[col]; ga[nt] = gam[col]; be4[nt] = bet[col];
  }
#pragma unroll
  for (int mt = 0; mt < 2; ++mt)
#pragma unroll
    for (int nt = 0; nt < 4; ++nt) {
      int col = w * 64 + nt * 16 + l15;
#pragma unroll
      for (int r = 0; r < 4; ++r) {
        int row = m0 + mt * 16 + quad * 4 + r;
        acc[mt][nt][r] += bi[nt] + R[(size_t)row * 256 + col];
      }
    }

  float s1[2][4], s2[2][4];
#pragma unroll
  for (int mt = 0; mt < 2; ++mt)
#pragma unroll
    for (int r = 0; r < 4; ++r) {
      float a = 0.f, b = 0.f;
#pragma unroll
      for (int nt = 0; nt < 4; ++nt) {
        float v = acc[mt][nt][r];
        a += v; b += v * v;
      }
      s1[mt][r] = a; s2[mt][r] = b;
    }
#pragma unroll
  for (int off = 1; off <= 8; off <<= 1)
#pragma unroll
    for (int mt = 0; mt < 2; ++mt)
#pragma unroll
      for (int r = 0; r < 4; ++r) {
        s1[mt][r] += __shfl_xor(s1[mt][r], off, 64);
        s2[mt][r] += __shfl_xor(s2[mt][r], off, 64);
      }
  if (l15 == 0) {
#pragma unroll
    for (int mt = 0; mt < 2; ++mt)
#pragma unroll
      for (int r = 0; r < 4; ++r) {
        int row32 = mt * 16 + quad * 4 + r;
        red[0][row32][w] = s1[mt][r];
        red[1][row32][w] = s2[mt][r];
      }
  }
  __syncthreads();

#pragma unroll
  for (int mt = 0; mt < 2; ++mt)
#pragma unroll
    for (int r = 0; r < 4; ++r) {
      int row32 = mt * 16 + quad * 4 + r;
      float4 sa = *(const float4*)&red[0][row32][0];
      float4 sb = *(const float4*)&red[1][row32][0];
      float sum = sa.x + sa.y + sa.z + sa.w;
      float sq  = sb.x + sb.y + sb.z + sb.w;
      float mu  = sum * (1.f / 256.f);
      float var = sq * (1.f / 256.f) - mu * mu;
      float rs  = 1.f / sqrtf(var + 1e-5f);
      int row = m0 + row32;
#pragma unroll
      for (int nt = 0; nt < 4; ++nt) {
        int col = w * 64 + nt * 16 + l15;
        float y = (acc[mt][nt][r] - mu) * rs * ga[nt] + be4[nt];
        size_t idx = (size_t)row * 256 + col;
        Yf[idx] = y;
        if (LN1) Yb[idx] = f2bf(y);
      }
    }
}

// ---------------------------------------------------------------------------
// One-shot prep: x cvt (blocks 0..1023), 4 square W transposes (1024..1279),
// Wf1 transpose (1280..1535), Wf2 transpose (1536..1791), bias concat (1792).
// ---------------------------------------------------------------------------
__global__ __launch_bounds__(256) void prep_k(
    const float* __restrict__ x, bf16u* __restrict__ xb,
    const float* __restrict__ Wq, const float* __restrict__ Wk,
    const float* __restrict__ Wv, const float* __restrict__ Wo,
    bf16u* __restrict__ Wqkvt, bf16u* __restrict__ Wot,
    const float* __restrict__ Wf1, bf16u* __restrict__ Wf1t,
    const float* __restrict__ Wf2, bf16u* __restrict__ Wf2t,
    const float* __restrict__ bq, const float* __restrict__ bk,
    const float* __restrict__ bv, float* __restrict__ bqkv)
{
  __shared__ float tile[32][33];
  const int bid = blockIdx.x;
  const int t = threadIdx.x;

  if (bid < 1024) {            // x fp32 -> bf16, 8 elems/thread
    int i = bid * 256 + t;
    float4 a = ((const float4*)x)[i * 2];
    float4 b = ((const float4*)x)[i * 2 + 1];
    uint4 o;
    o.x = f2bf(a.x) | ((unsigned)f2bf(a.y) << 16);
    o.y = f2bf(a.z) | ((unsigned)f2bf(a.w) << 16);
    o.z = f2bf(b.x) | ((unsigned)f2bf(b.y) << 16);
    o.w = f2bf(b.z) | ((unsigned)f2bf(b.w) << 16);
    ((uint4*)xb)[i] = o;
  } else if (bid < 1792) {     // transpose+convert, 32x32 tiles
    const float* src; bf16u* dst; int K, N, kb, nb;
    int rr = bid - 1024;
    if (rr < 256) {
      int z = rr >> 6, i = rr & 63;
      src = (z == 0) ? Wq : (z == 1) ? Wk : (z == 2) ? Wv : Wo;
      dst = (z == 0) ? Wqkvt : (z == 1) ? Wqkvt + 65536
          : (z == 2) ? Wqkvt + 131072 : Wot;
      K = 256; N = 256; kb = (i & 7) * 32; nb = (i >> 3) * 32;
    } else if (rr < 512) {
      int i = rr - 256;
      src = Wf1; dst = Wf1t; K = 256; N = 1024;
      kb = (i & 7) * 32; nb = (i >> 3) * 32;
    } else {
      int i = rr - 512;
      src = Wf2; dst = Wf2t; K = 1024; N = 256;
      kb = (i & 31) * 32; nb = (i >> 5) * 32;
    }
    const int tx = t & 31, ty = t >> 5;
#pragma unroll
    for (int r = 0; r < 4; ++r)
      tile[ty + 8 * r][tx] = src[(size_t)(kb + ty + 8 * r) * N + nb + tx];
    __syncthreads();
#pragma unroll
    for (int r = 0; r < 4; ++r)
      dst[(size_t)(nb + ty + 8 * r) * K + kb + tx] = f2bf(tile[tx][ty + 8 * r]);
  } else {                     // bias concat
    for (int i = t; i < 768; i += 256)
      bqkv[i] = (i < 256) ? bq[i] : (i < 512) ? bk[i - 256] : bv[i - 512];
  }
}

// ---------------------------------------------------------------------------
// MFMA flash attention (unchanged from round 3 — passing, 62 us).
// ---------------------------------------------------------------------------
__global__ __launch_bounds__(256) void attn_k(
    const bf16u* __restrict__ qkv, const int* __restrict__ sb,
    const unsigned char* __restrict__ mask, const float* __restrict__ be,
    bf16u* __restrict__ O)
{
  __shared__ bf16u Kl[2][64][40];
  __shared__ bf16u Vt[2][16][72];
  __shared__ bf16u Pl[4][16][40];
  __shared__ float embl[2][6];

  const int t    = threadIdx.x;
  const int b    = blockIdx.z;
  const int hg   = blockIdx.y;
  const int w    = t >> 6;
  const int lane = t & 63;
  const int l15  = lane & 15;
  const int quad = lane >> 4;
  const int q0w  = blockIdx.x * 64 + w * 16;

  if (t < 12) embl[t / 6][t % 6] = be[(t % 6) * 16 + hg * 2 + t / 6];

  {
    float4 z = {0.f, 0.f, 0.f, 0.f};
    float4* kp = (float4*)&Kl[0][0][0];
    for (int i = t; i < 640; i += 256) kp[i] = z;
  }

  short8 qf[2];
#pragma unroll
  for (int hp = 0; hp < 2; ++hp) {
    uint4 v = {0u, 0u, 0u, 0u};
    if (quad < 2)
      v = *(const uint4*)(qkv + ((size_t)(b * E_) + q0w + l15) * 768 +
                          (hg * 2 + hp) * 16 + quad * 8);
    else if (quad == 2)
      v.x = 0x3F80u;
    union { uint4 u; short8 s; } c; c.u = v;
    qf[hp] = c.s;
  }

  const int s_hp   = t >> 7;
  const int s_key  = (t >> 1) & 63;
  const int s_half = t & 1;
  const size_t kvbase = (size_t)b * E_ * 768;
  const int* sbp = sb + ((size_t)b * E_ + q0w) * E_;

  f32x4 accO[2];
  const f32x4 z4 = {0.f, 0.f, 0.f, 0.f};
  accO[0] = z4; accO[1] = z4;
  float lsum[2][4] = {};

  for (int k0 = 0; k0 < E_; k0 += 64) {
    int sbv[2][2][4];
#pragma unroll
    for (int s2 = 0; s2 < 2; ++s2)
#pragma unroll
      for (int f = 0; f < 2; ++f)
#pragma unroll
        for (int r = 0; r < 4; ++r)
          sbv[s2][f][r] = sbp[(size_t)(quad * 4 + r) * E_ + k0 + s2 * 32 + f * 16 + l15];

    __syncthreads();
    {
      const bf16u* kq = qkv + kvbase + (size_t)(k0 + s_key) * 768 + 256 +
                        (hg * 2 + s_hp) * 16 + s_half * 8;
      uint4 kw = *(const uint4*)kq;
      uint4 vw = *(const uint4*)(kq + 256);
      *(uint4*)&Kl[s_hp][s_key][s_half * 8] = kw;
      const int col = (s_key >> 5) * 32 + ((s_key & 15) << 1) + ((s_key >> 4) & 1);
      union { uint4 u; bf16u e[8]; } vc; vc.u = vw;
#pragma unroll
      for (int j = 0; j < 8; ++j)
        Vt[s_hp][s_half * 8 + j][col] = vc.e[j];
      if (s_half == 0) {
        unsigned char mv = mask[b * E_ + k0 + s_key];
        Kl[s_hp][s_key][16] = mv ? (bf16u)0xCF6E : (bf16u)0;
      }
    }
    __syncthreads();

#pragma unroll
    for (int hp = 0; hp < 2; ++hp) {
#pragma unroll
      for (int s2 = 0; s2 < 2; ++s2) {
        short8 kf0 = *(const short8*)&Kl[hp][s2 * 32 + l15][quad * 8];
        short8 kf1 = *(const short8*)&Kl[hp][s2 * 32 + 16 + l15][quad * 8];
        f32x4 sc0 = __builtin_amdgcn_mfma_f32_16x16x32_bf16(qf[hp], kf0, z4, 0, 0, 0);
        f32x4 sc1 = __builtin_amdgcn_mfma_f32_16x16x32_bf16(qf[hp], kf1, z4, 0, 0, 0);
#pragma unroll
        for (int r = 0; r < 4; ++r) {
          float w0 = embl[hp][sbv[s2][0][r]];
          float w1 = embl[hp][sbv[s2][1][r]];
          float p0 = __expf(fmaf(sc0[r], 0.25f, w0));
          float p1 = __expf(fmaf(sc1[r], 0.25f, w1));
          unsigned u0 = __float_as_uint(p0) & 0xffff0000u;
          unsigned u1 = __float_as_uint(p1) & 0xffff0000u;
          lsum[hp][r] += __uint_as_float(u0) + __uint_as_float(u1);
          *(unsigned*)&Pl[w][quad * 4 + r][l15 * 2] = (__float_as_uint(p0) >> 16) | u1;
        }
        short8 pf = *(const short8*)&Pl[w][l15][quad * 8];
        short8 vf = *(const short8*)&Vt[hp][l15][s2 * 32 + quad * 8];
        accO[hp] = __builtin_amdgcn_mfma_f32_16x16x32_bf16(pf, vf, accO[hp], 0, 0, 0);
      }
    }
  }

#pragma unroll
  for (int off = 1; off <= 8; off <<= 1)
#pragma unroll
    for (int hp = 0; hp < 2; ++hp)
#pragma unroll
      for (int r = 0; r < 4; ++r)
        lsum[hp][r] += __shfl_xor(lsum[hp][r], off, 64);

#pragma unroll
  for (int hp = 0; hp < 2; ++hp) {
#pragma unroll
    for (int r = 0; r < 4; ++r) {
      float o = accO[hp][r] / lsum[hp][r];
      O[((size_t)(b * E_) + q0w + quad * 4 + r) * 256 + (hg * 2 + hp) * 16 + l15] = f2bf(o);
    }
  }
}

// ---------------------------------------------------------------------------
extern "C" void kernel_launch(void* const* d_in, const int* in_sizes, int n_in,
                              void* d_out, int out_size, void* d_ws, size_t ws_size,
                              hipStream_t stream) {
  const float* x   = (const float*)d_in[0];
  const int*   sb  = (const int*)d_in[1];
  const unsigned char* mask = (const unsigned char*)d_in[2];
  const float* Wq  = (const float*)d_in[3];
  const float* bq  = (const float*)d_in[4];
  const float* Wk  = (const float*)d_in[5];
  const float* bk  = (const float*)d_in[6];
  const float* Wv  = (const float*)d_in[7];
  const float* bv  = (const float*)d_in[8];
  const float* Wo  = (const float*)d_in[9];
  const float* bo  = (const float*)d_in[10];
  const float* be  = (const float*)d_in[11];
  const float* g1  = (const float*)d_in[12];
  const float* b1  = (const float*)d_in[13];
  const float* Wf1 = (const float*)d_in[14];
  const float* bf1 = (const float*)d_in[15];
  const float* Wf2 = (const float*)d_in[16];
  const float* bf2 = (const float*)d_in[17];
  const float* g2  = (const float*)d_in[18];
  const float* b2  = (const float*)d_in[19];
  float* out = (float*)d_out;

  // workspace layout (byte offsets); peak ~35.7 MB
  char* ws = (char*)d_ws;
  bf16u* Wqkvt = (bf16u*)(ws + 0);          // 768*256*2
  bf16u* Wot   = (bf16u*)(ws + 393216);     // 256*256*2
  bf16u* Wf1t  = (bf16u*)(ws + 524288);     // 1024*256*2
  bf16u* Wf2t  = (bf16u*)(ws + 1048576);    // 256*1024*2
  float* bqkv  = (float*)(ws + 1572864);    // 768*4
  bf16u* xb    = (bf16u*)(ws + 2097152);    // 4 MB   [dead after qkv gemm]
  bf16u* qkv   = (bf16u*)(ws + 6291456);    // 12 MB  [dead after attn]
  bf16u* att   = (bf16u*)(ws + 18874368);   // 4 MB   [dead after wo gemm]
  float* x1    = (float*)(ws + 23068672);   // 8 MB
  bf16u* x1b   = (bf16u*)(ws + 31457280);   // 4 MB
  bf16u* ffh   = (bf16u*)(ws + 2097152);    // 16 MB, reuses xb+qkv

  dim3 blk(256);

  prep_k<<<1793, blk, 0, stream>>>(x, xb, Wq, Wk, Wv, Wo, Wqkvt, Wot,
                                   Wf1, Wf1t, Wf2, Wf2t, bq, bk, bv, bqkv);

  // QKV projection (fused, N=768) -> qkv bf16
  mm_k<128, 128, 0><<<dim3(64, 6), blk, 0, stream>>>(xb, Wqkvt, bqkv, nullptr,
                                                     qkv, M_, 768, 256);
  // MFMA flash attention -> att bf16
  attn_k<<<dim3(16, 8, 8), blk, 0, stream>>>(qkv, sb, mask, be, att);

  // Wo GEMM + bias + residual(x) + LN1 -> x1 fp32, x1b bf16
  mm_ln_k<256, 1><<<256, blk, 0, stream>>>(att, Wot, bo, x, g1, b1, x1, x1b);

  // FF1 + gelu -> ffh bf16
  mm_k<128, 128, 2><<<dim3(64, 8), blk, 0, stream>>>(x1b, Wf1t, bf1, nullptr,
                                                     ffh, M_, 1024, 256);
  // FF2 + bias + residual(x1) + LN2 -> out fp32
  mm_ln_k<1024, 0><<<256, blk, 0, stream>>>(ffh, Wf2t, bf2, x1, g2, b2, out, nullptr);
}